// Round 2
// baseline (95738.043 us; speedup 1.0000x reference)
//
#include <hip/hip_runtime.h>
#include <math.h>

#define NS 1024
#define SENT (-1.0e300)

template <typename T> struct V2;
template <> struct V2<double> { using t = double2; };
template <> struct V2<float>  { using t = float2; };

__device__ __forceinline__ double ald(const double* p) {
  return __hip_atomic_load(p, __ATOMIC_RELAXED, __HIP_MEMORY_SCOPE_AGENT);
}
template <typename T>
__device__ __forceinline__ void ast(T* p, T v) {
  __hip_atomic_store(p, v, __ATOMIC_RELAXED, __HIP_MEMORY_SCOPE_AGENT);
}

// ---------------------------------------------------------------- init
template <typename TR>
__global__ void k_init(double* __restrict__ wbuf, TR* __restrict__ Rlast,
                       int* __restrict__ bars, int nbar) {
  int stride = gridDim.x * blockDim.x;
  int t = blockIdx.x * blockDim.x + threadIdx.x;
  for (int idx = t; idx < nbar; idx += stride) bars[idx] = 0;
  for (int idx = t; idx < (NS + 1) * 128; idx += stride)
    wbuf[idx] = (idx < 128) ? ((idx == 0) ? 1.0 : 0.0) : SENT;
  for (int idx = t; idx < 128 * 128; idx += stride)
    Rlast[idx] = (TR)((idx == 0) ? 1.0f : 0.0f);
}

// ---------------------------------------------------------------- cayley
// G = I + 0.5(X1-X1^T) + 0.25 X2^T X2 ; Y = G^{-1} (pivot-free GJ; sym(G)>=I).
// W_top = 2Y - I -> Tk ; Y -> Yscr (aliases Rbuf, consumed by k_w2 before init).
template <typename TT, typename TR>
__global__ __launch_bounds__(256) void k_cayley(const float* __restrict__ params,
                                                TT* __restrict__ Tk,
                                                TR* __restrict__ Yscr) {
  __shared__ float XB[64 * 132];
  __shared__ double prow[128], fcol[128];
  const int site = blockIdx.x, tid = threadIdx.x;
  const float* X = params + (size_t)site * 256 * 128;
  const int ti = tid >> 4, tj = tid & 15;
  const int R0 = ti * 8, C0 = tj * 8;
  double g[8][8];
  #pragma unroll
  for (int i = 0; i < 8; ++i)
    #pragma unroll
    for (int j = 0; j < 8; ++j) g[i][j] = ((R0 + i) == (C0 + j)) ? 1.0 : 0.0;
  // X1 in two 64-row chunks: g += 0.5*(X1[r][c] - X1[c][r])
  for (int h = 0; h < 2; ++h) {
    for (int idx = tid; idx < 64 * 128; idx += 256) {
      int rr = idx >> 7, c = idx & 127;
      XB[rr * 132 + c] = X[(size_t)(h * 64 + rr) * 128 + c];
    }
    __syncthreads();
    int lo = h * 64;
    if ((R0 >> 6) == h) {
      #pragma unroll
      for (int i = 0; i < 8; ++i)
        #pragma unroll
        for (int j = 0; j < 8; ++j)
          g[i][j] += 0.5 * (double)XB[(R0 + i - lo) * 132 + (C0 + j)];
    }
    if ((C0 >> 6) == h) {
      #pragma unroll
      for (int i = 0; i < 8; ++i)
        #pragma unroll
        for (int j = 0; j < 8; ++j)
          g[i][j] -= 0.5 * (double)XB[(C0 + j - lo) * 132 + (R0 + i)];
    }
    __syncthreads();
  }
  // X2 rank update in two 64-row chunks
  for (int h = 0; h < 2; ++h) {
    for (int idx = tid; idx < 64 * 128; idx += 256) {
      int rr = idx >> 7, c = idx & 127;
      XB[rr * 132 + c] = X[(size_t)(128 + h * 64 + rr) * 128 + c];
    }
    __syncthreads();
    for (int a = 0; a < 64; ++a) {
      double fa[8], fb[8];
      #pragma unroll
      for (int i = 0; i < 8; ++i) fa[i] = 0.5 * (double)XB[a * 132 + R0 + i];
      #pragma unroll
      for (int j = 0; j < 8; ++j) fb[j] = 0.5 * (double)XB[a * 132 + C0 + j];
      #pragma unroll
      for (int i = 0; i < 8; ++i)
        #pragma unroll
        for (int j = 0; j < 8; ++j) g[i][j] += fa[i] * fb[j];
    }
    __syncthreads();
  }
  // in-place Gauss-Jordan inverse, no pivoting
  for (int p = 0; p < 128; ++p) {
    int pb = p >> 3, pl = p & 7;
    if (ti == pb) {
      #pragma unroll
      for (int j = 0; j < 8; ++j) prow[C0 + j] = g[pl][j];
    }
    if (tj == pb) {
      #pragma unroll
      for (int i = 0; i < 8; ++i) fcol[R0 + i] = g[i][pl];
    }
    __syncthreads();
    double d = 1.0 / prow[p];
    double pd[8];
    #pragma unroll
    for (int j = 0; j < 8; ++j) pd[j] = prow[C0 + j] * d;
    #pragma unroll
    for (int i = 0; i < 8; ++i) {
      int r = R0 + i;
      if (r == p) {
        #pragma unroll
        for (int j = 0; j < 8; ++j) g[i][j] = ((C0 + j) == p) ? d : pd[j];
      } else {
        double f = fcol[r];
        #pragma unroll
        for (int j = 0; j < 8; ++j)
          g[i][j] = ((C0 + j) == p) ? (-f * d) : (g[i][j] - f * pd[j]);
      }
    }
    __syncthreads();
  }
  TR* Ys = Yscr + (size_t)site * 16384;
  TT* Ts = Tk + (size_t)site * 32768;
  #pragma unroll
  for (int i = 0; i < 8; ++i) {
    int r = R0 + i, s = r & 1, a = r >> 1;
    #pragma unroll
    for (int j = 0; j < 8; ++j) {
      int c = C0 + j;
      Ys[(size_t)r * 128 + c] = (TR)g[i][j];
      Ts[((size_t)s * 128 + a) * 128 + c] =
          (TT)(2.0 * g[i][j] - ((r == c) ? 1.0 : 0.0));
    }
  }
}

// ---------------------------------------------------------------- W_bot = -X2 * Y
template <typename TT, typename TR>
__global__ __launch_bounds__(256) void k_w2(const float* __restrict__ params,
                                            const TR* __restrict__ Yscr,
                                            TT* __restrict__ Tk) {
  __shared__ float X2c[16 * 132];   // [bb][r]
  __shared__ double Yt[16 * 130];   // [bb][c]
  const int site = blockIdx.x, tid = threadIdx.x;
  const float* X2g = params + (size_t)site * 256 * 128 + 128 * 128;
  const TR* Ys = Yscr + (size_t)site * 16384;
  TT* Ts = Tk + (size_t)site * 32768;
  const int ti = tid >> 4, tj = tid & 15;
  const int R0 = ti * 8, C0 = tj * 8;
  double acc[8][8];
  #pragma unroll
  for (int i = 0; i < 8; ++i)
    #pragma unroll
    for (int j = 0; j < 8; ++j) acc[i][j] = 0.0;
  for (int b0 = 0; b0 < 128; b0 += 16) {
    __syncthreads();
    for (int idx = tid; idx < 2048; idx += 256) {
      int r = idx >> 4, bb = idx & 15;
      X2c[bb * 132 + r] = X2g[(size_t)r * 128 + b0 + bb];
    }
    for (int idx = tid; idx < 2048; idx += 256) {
      int bb = idx >> 7, c = idx & 127;
      Yt[bb * 130 + c] = (double)Ys[(size_t)(b0 + bb) * 128 + c];
    }
    __syncthreads();
    for (int bb = 0; bb < 16; ++bb) {
      double xf[8], yf[8];
      #pragma unroll
      for (int i = 0; i < 8; ++i) xf[i] = (double)X2c[bb * 132 + R0 + i];
      #pragma unroll
      for (int j = 0; j < 8; ++j) yf[j] = Yt[bb * 130 + C0 + j];
      #pragma unroll
      for (int i = 0; i < 8; ++i)
        #pragma unroll
        for (int j = 0; j < 8; ++j) acc[i][j] += xf[i] * yf[j];
    }
  }
  #pragma unroll
  for (int i = 0; i < 8; ++i) {
    int r = 128 + R0 + i, s = r & 1, a = r >> 1;
    #pragma unroll
    for (int j = 0; j < 8; ++j)
      Ts[((size_t)s * 128 + a) * 128 + C0 + j] = (TT)(-acc[i][j]);
  }
}

// ---------------------------------------------------------------- grid barrier (256 WGs)
__device__ __forceinline__ void gbar(int* bars, int bid, int w, int tid) {
  __threadfence();
  __syncthreads();
  if (tid == 0) {
    int* base = bars + bid * 40;
    int old = __hip_atomic_fetch_add(base + (w >> 3), 1, __ATOMIC_ACQ_REL,
                                     __HIP_MEMORY_SCOPE_AGENT);
    if (old == 7)
      __hip_atomic_fetch_add(base + 32, 1, __ATOMIC_ACQ_REL,
                             __HIP_MEMORY_SCOPE_AGENT);
    while (__hip_atomic_load(base + 32, __ATOMIC_ACQUIRE,
                             __HIP_MEMORY_SCOPE_AGENT) < 32)
      __builtin_amdgcn_s_sleep(2);
  }
  __syncthreads();
  __builtin_amdgcn_fence(__ATOMIC_ACQUIRE, "agent");
}

// ---------------------------------------------------------------- reverse scan
// step i: P[(j,a)][e] = sum_b K[j,a,b] Rin[b,e]; Rout[a][c] = sum_{j,e} P[j,a,e] K[j,c,e]
template <typename TT, typename TR>
__global__ __launch_bounds__(256) void k_scan(const TT* __restrict__ Tk,
                                              TR* __restrict__ Rbuf,
                                              double* __restrict__ Pscr,
                                              TR* __restrict__ Rs0,
                                              double* __restrict__ Zp,
                                              int* __restrict__ bars) {
  __shared__ double B0[16 * 130];   // A: KA rows  | B: PT rows
  __shared__ double B1[8 * 130];    // A: RB cols
  __shared__ double B2[16 * 130];   // B: KT rows (prefetched)
  __shared__ double red[1024];
  const int w = blockIdx.x, tid = threadIdx.x;
  const int grpA = w >> 4, bt = w & 15;           // stage A: 16 P-rows x 8 cols
  const int a0 = (w >> 4) * 8, c0 = (w & 15) * 8; // stage B: 8 x 8 tile
  for (int i = NS - 1; i >= 0; --i) {
    const TT* K = Tk + (size_t)i * 32768;
    const TR* Rin = Rbuf + (size_t)i * 16384;
    // ---- stage A loads ----
    for (int idx = tid; idx < 2048; idx += 256) {
      int rr = idx >> 7, d = idx & 127;
      B0[rr * 130 + d] = (double)K[(size_t)(grpA * 16 + rr) * 128 + d];
    }
    for (int idx = tid; idx < 1024; idx += 256) {
      int d = idx >> 3, bb = idx & 7;
      B1[bb * 130 + d] = (double)Rin[(size_t)d * 128 + bt * 8 + bb];
    }
    __syncthreads();
    // ---- stage A dot: 2x2 block, d-eighth ----
    {
      int dq = tid >> 5, rp = (tid >> 2) & 7, bp = tid & 3;
      int d0 = dq * 16;
      double a00 = 0, a01 = 0, a10 = 0, a11 = 0;
      #pragma unroll
      for (int m = 0; m < 16; ++m) {
        int d = d0 + m;
        double ka0 = B0[(2 * rp) * 130 + d], ka1 = B0[(2 * rp + 1) * 130 + d];
        double rb0 = B1[(2 * bp) * 130 + d], rb1 = B1[(2 * bp + 1) * 130 + d];
        a00 += ka0 * rb0; a01 += ka0 * rb1; a10 += ka1 * rb0; a11 += ka1 * rb1;
      }
      red[tid * 4 + 0] = a00; red[tid * 4 + 1] = a01;
      red[tid * 4 + 2] = a10; red[tid * 4 + 3] = a11;
    }
    __syncthreads();
    if (tid < 128) {  // combine 8 d-partials per output
      int rr = tid >> 3, bb = tid & 7;
      int rp = rr >> 1, ii = rr & 1, bp = bb >> 1, jj = bb & 1;
      double s = 0;
      #pragma unroll
      for (int dq = 0; dq < 8; ++dq)
        s += red[(dq * 32 + rp * 4 + bp) * 4 + ii * 2 + jj];
      ast(&Pscr[(size_t)(grpA * 16 + rr) * 128 + bt * 8 + bb], s);
    }
    // prefetch stage-B K tile (independent of P) before the barrier
    for (int idx = tid; idx < 2048; idx += 256) {
      int row = idx >> 7, b = idx & 127;
      int j = row >> 3, cc = row & 7;
      B2[row * 130 + b] = (double)K[(size_t)(j * 128 + c0 + cc) * 128 + b];
    }
    int bid = (NS - 1 - i) << 1;
    gbar(bars, bid, w, tid);
    // ---- stage B loads ----
    for (int idx = tid; idx < 2048; idx += 256) {
      int row = idx >> 7, b = idx & 127;
      int j = row >> 3, aa = row & 7;
      B0[row * 130 + b] = Pscr[(size_t)(j * 128 + a0 + aa) * 128 + b];
    }
    __syncthreads();
    // ---- stage B dot: 2x2 block, (j,b)-sixteenth ----
    {
      int dh = tid >> 4, ap = (tid >> 2) & 3, cp = tid & 3;
      int j = dh >> 3, bb0 = (dh & 7) * 16;
      double a00 = 0, a01 = 0, a10 = 0, a11 = 0;
      #pragma unroll
      for (int m = 0; m < 16; ++m) {
        int b = bb0 + m;
        double pa0 = B0[(j * 8 + 2 * ap) * 130 + b], pa1 = B0[(j * 8 + 2 * ap + 1) * 130 + b];
        double kb0 = B2[(j * 8 + 2 * cp) * 130 + b], kb1 = B2[(j * 8 + 2 * cp + 1) * 130 + b];
        a00 += pa0 * kb0; a01 += pa0 * kb1; a10 += pa1 * kb0; a11 += pa1 * kb1;
      }
      red[tid * 4 + 0] = a00; red[tid * 4 + 1] = a01;
      red[tid * 4 + 2] = a10; red[tid * 4 + 3] = a11;
    }
    __syncthreads();
    if (tid < 64) {
      int aa = tid >> 3, cc = tid & 7;
      int ap = aa >> 1, ii = aa & 1, cp = cc >> 1, jj = cc & 1;
      double s = 0;
      #pragma unroll
      for (int dh = 0; dh < 16; ++dh)
        s += red[(dh * 16 + ap * 4 + cp) * 4 + ii * 2 + jj];
      TR* outp = (i > 0) ? (Rbuf + (size_t)(i - 1) * 16384) : Rs0;
      ast(&outp[(size_t)(a0 + aa) * 128 + c0 + cc], (TR)s);
      if (i == 0 && w == 0 && tid == 0) *Zp = s;
    }
    gbar(bars, bid + 1, w, tid);
  }
}

// ---------------------------------------------------------------- sampling sweep
// L = w w^T rank-1: y_s = T_s^T w ; ps0 = y_1^T R y_1 (site0: /Z);
// w' = y_k / sqrt(p * (site0 ? Z : 1)). R held in registers; w via sentinel poll.
template <typename TT, typename TR>
__global__ __launch_bounds__(1024) void k_sample(const TT* __restrict__ Tk,
                                                 const TR* __restrict__ Rbuf,
                                                 double* __restrict__ wbuf,
                                                 const double* __restrict__ Zp,
                                                 const float* __restrict__ randu,
                                                 float* __restrict__ out) {
  __shared__ double wl[128], yl[256], zl[128], part[1024], ctrl[2];
  const int g = blockIdx.x, tid = threadIdx.x;
  const int s = tid >> 9, q = (tid >> 7) & 3, b = tid & 127;
  const int lane = tid & 63, wv = tid >> 6;
  using TR2 = typename V2<TR>::t;
  for (int site = g; site < NS; site += 16) {
    const TT* T = Tk + (size_t)site * 32768;
    double tf[32];
    {
      const TT* tp = T + ((size_t)s * 128 + q * 32) * 128 + b;
      #pragma unroll
      for (int t = 0; t < 32; ++t) tf[t] = (double)tp[(size_t)t * 128];
    }
    double rv[16];  // R rows 16t+wv, cols 2*lane, 2*lane+1
    {
      const TR2* R2 = (const TR2*)(Rbuf + (size_t)site * 16384);
      #pragma unroll
      for (int t = 0; t < 8; ++t) {
        TR2 v = R2[t * 1024 + tid];
        rv[2 * t] = (double)v.x; rv[2 * t + 1] = (double)v.y;
      }
    }
    if (tid < 128) {  // poll w (payload-is-flag)
      double* wp = wbuf + (size_t)site * 128 + tid;
      double v;
      do { v = ald(wp); } while (v == SENT);
      wl[tid] = v;
    }
    __syncthreads();
    {  // y_s[b] partials over a-quarter
      double p0 = 0.0;
      #pragma unroll
      for (int t = 0; t < 32; ++t) p0 += tf[t] * wl[q * 32 + t];
      part[(s * 4 + q) * 128 + b] = p0;
    }
    __syncthreads();
    if (tid < 256) {
      int ss = tid >> 7, bb = tid & 127;
      yl[ss * 128 + bb] = part[(ss * 4) * 128 + bb] + part[(ss * 4 + 1) * 128 + bb] +
                          part[(ss * 4 + 2) * 128 + bb] + part[(ss * 4 + 3) * 128 + bb];
    }
    __syncthreads();
    {  // z = R y1 via register rows + wave butterflies
      double y1a = yl[128 + 2 * lane], y1b = yl[128 + 2 * lane + 1];
      #pragma unroll
      for (int t = 0; t < 8; ++t) {
        double pz = rv[2 * t] * y1a + rv[2 * t + 1] * y1b;
        #pragma unroll
        for (int off = 1; off < 64; off <<= 1) pz += __shfl_xor(pz, off, 64);
        if (lane == 0) zl[16 * t + wv] = pz;
      }
    }
    __syncthreads();
    if (tid < 128) part[tid] = zl[tid] * yl[128 + tid];
    __syncthreads();
    if (tid < 64) {
      double v = part[tid] + part[tid + 64];
      #pragma unroll
      for (int off = 1; off < 64; off <<= 1) v += __shfl_xor(v, off, 64);
      if (tid == 0) {
        double zn = (site == 0) ? *Zp : 1.0;
        double ps0 = v / zn;
        double u = (double)randu[site];
        bool take0 = u < ps0;
        double pp = take0 ? ps0 : (1.0 - ps0);
        ctrl[0] = take0 ? 1.0 : 0.0;
        ctrl[1] = 1.0 / sqrt(pp * zn);   // site0: w' = y_k/sqrt(p_u), p_u = pp*Z
        out[2 * site] = take0 ? 0.0f : 1.0f;
        out[2 * site + 1] = take0 ? 1.0f : 0.0f;
      }
    }
    __syncthreads();
    {
      int k = (ctrl[0] != 0.0) ? 1 : 0;
      double sc = ctrl[1];
      if (tid < 128)
        ast(&wbuf[(size_t)(site + 1) * 128 + tid], yl[k * 128 + tid] * sc);
    }
    __syncthreads();
  }
}

// ---------------------------------------------------------------- diagnostics
__global__ void k_diag(float* __restrict__ out, int n, float mb) {
  int i = blockIdx.x * blockDim.x + threadIdx.x;
  if (i < n) out[i] = (i == 0) ? mb : ((i & 1) ? 0.75f : 0.25f);
}

// ---------------------------------------------------------------- launch
template <typename TT, typename TR>
struct Plan {
  size_t oTk, oR, oRs0, oP, oW, oB, oZ, need;
  Plan() {
    oTk = 0;
    oR = oTk + sizeof(TT) * (size_t)NS * 32768;
    oRs0 = oR + sizeof(TR) * (size_t)NS * 16384;   // Rbuf; also aliases Yscr
    oP = oRs0 + sizeof(TR) * 16384;
    oW = oP + 8ull * 256 * 128;
    oB = oW + 8ull * (NS + 1) * 128;
    oZ = oB + 4ull * 2048 * 40;
    need = oZ + 64;
  }
};

template <typename TT, typename TR>
static void run_cfg(const float* params, const float* randu, float* out,
                    char* ws, hipStream_t stream) {
  Plan<TT, TR> P;
  TT* Tk = (TT*)(ws + P.oTk);
  TR* Rbuf = (TR*)(ws + P.oR);
  TR* Yscr = Rbuf;  // Y consumed by k_w2 before k_init/k_scan touch Rbuf
  TR* Rs0 = (TR*)(ws + P.oRs0);
  double* Pscr = (double*)(ws + P.oP);
  double* wbuf = (double*)(ws + P.oW);
  int* bars = (int*)(ws + P.oB);
  double* Zp = (double*)(ws + P.oZ);
  k_cayley<TT, TR><<<dim3(NS), dim3(256), 0, stream>>>(params, Tk, Yscr);
  k_w2<TT, TR><<<dim3(NS), dim3(256), 0, stream>>>(params, Yscr, Tk);
  k_init<TR><<<dim3(256), dim3(256), 0, stream>>>(
      wbuf, Rbuf + (size_t)(NS - 1) * 16384, bars, 2048 * 40);
  k_scan<TT, TR><<<dim3(256), dim3(256), 0, stream>>>(Tk, Rbuf, Pscr, Rs0, Zp, bars);
  k_sample<TT, TR><<<dim3(16), dim3(1024), 0, stream>>>(Tk, Rbuf, wbuf, Zp, randu, out);
}

extern "C" void kernel_launch(void* const* d_in, const int* in_sizes, int n_in,
                              void* d_out, int out_size, void* d_ws, size_t ws_size,
                              hipStream_t stream) {
  const float* params = (const float*)d_in[0];
  const float* randu = (const float*)d_in[1];
  float* out = (float*)d_out;
  char* ws = (char*)d_ws;
  if (ws_size >= Plan<double, double>().need) {
    run_cfg<double, double>(params, randu, out, ws, stream);
  } else if (ws_size >= Plan<float, double>().need) {
    run_cfg<float, double>(params, randu, out, ws, stream);
  } else if (ws_size >= Plan<float, float>().need) {
    run_cfg<float, float>(params, randu, out, ws, stream);
  } else {
    // diagnostic signature: absmax ~= workspace MB (distinct from 1.0)
    k_diag<<<dim3((out_size + 255) / 256), dim3(256), 0, stream>>>(
        out, out_size, (float)(ws_size >> 20));
  }
}

// Round 3
// 21675.156 us; speedup vs baseline: 4.4169x; 4.4169x over previous
//
#include <hip/hip_runtime.h>
#include <math.h>

#define NS 1024
#define SENT (-1.0e300)

template <typename T> struct V2;
template <> struct V2<double> { using t = double2; };
template <> struct V2<float>  { using t = float2; };

template <typename T>
__device__ __forceinline__ T aldT(const T* p) {
  return __hip_atomic_load(p, __ATOMIC_RELAXED, __HIP_MEMORY_SCOPE_AGENT);
}
__device__ __forceinline__ double ald(const double* p) {
  return __hip_atomic_load(p, __ATOMIC_RELAXED, __HIP_MEMORY_SCOPE_AGENT);
}
template <typename T>
__device__ __forceinline__ void ast(T* p, T v) {
  __hip_atomic_store(p, v, __ATOMIC_RELAXED, __HIP_MEMORY_SCOPE_AGENT);
}

// ---------------------------------------------------------------- init
template <typename TR>
__global__ void k_init(double* __restrict__ wbuf, TR* __restrict__ Rlast,
                       int* __restrict__ bars, int nbar) {
  int stride = gridDim.x * blockDim.x;
  int t = blockIdx.x * blockDim.x + threadIdx.x;
  for (int idx = t; idx < nbar; idx += stride) bars[idx] = 0;
  for (int idx = t; idx < (NS + 1) * 128; idx += stride)
    wbuf[idx] = (idx < 128) ? ((idx == 0) ? 1.0 : 0.0) : SENT;
  for (int idx = t; idx < 128 * 128; idx += stride)
    Rlast[idx] = (TR)((idx == 0) ? 1.0f : 0.0f);
}

// ---------------------------------------------------------------- cayley
// G = I + 0.5(X1-X1^T) + 0.25 X2^T X2 ; Y = G^{-1} (pivot-free GJ; sym(G)>=I).
// W_top = 2Y - I -> Tk ; Y -> Yscr (aliases Rbuf, consumed by k_w2 before init).
template <typename TT, typename TR>
__global__ __launch_bounds__(256) void k_cayley(const float* __restrict__ params,
                                                TT* __restrict__ Tk,
                                                TR* __restrict__ Yscr) {
  __shared__ float XB[64 * 132];
  __shared__ double prow[128], fcol[128];
  const int site = blockIdx.x, tid = threadIdx.x;
  const float* X = params + (size_t)site * 256 * 128;
  const int ti = tid >> 4, tj = tid & 15;
  const int R0 = ti * 8, C0 = tj * 8;
  double g[8][8];
  #pragma unroll
  for (int i = 0; i < 8; ++i)
    #pragma unroll
    for (int j = 0; j < 8; ++j) g[i][j] = ((R0 + i) == (C0 + j)) ? 1.0 : 0.0;
  for (int h = 0; h < 2; ++h) {
    for (int idx = tid; idx < 64 * 128; idx += 256) {
      int rr = idx >> 7, c = idx & 127;
      XB[rr * 132 + c] = X[(size_t)(h * 64 + rr) * 128 + c];
    }
    __syncthreads();
    int lo = h * 64;
    if ((R0 >> 6) == h) {
      #pragma unroll
      for (int i = 0; i < 8; ++i)
        #pragma unroll
        for (int j = 0; j < 8; ++j)
          g[i][j] += 0.5 * (double)XB[(R0 + i - lo) * 132 + (C0 + j)];
    }
    if ((C0 >> 6) == h) {
      #pragma unroll
      for (int i = 0; i < 8; ++i)
        #pragma unroll
        for (int j = 0; j < 8; ++j)
          g[i][j] -= 0.5 * (double)XB[(C0 + j - lo) * 132 + (R0 + i)];
    }
    __syncthreads();
  }
  for (int h = 0; h < 2; ++h) {
    for (int idx = tid; idx < 64 * 128; idx += 256) {
      int rr = idx >> 7, c = idx & 127;
      XB[rr * 132 + c] = X[(size_t)(128 + h * 64 + rr) * 128 + c];
    }
    __syncthreads();
    for (int a = 0; a < 64; ++a) {
      double fa[8], fb[8];
      #pragma unroll
      for (int i = 0; i < 8; ++i) fa[i] = 0.5 * (double)XB[a * 132 + R0 + i];
      #pragma unroll
      for (int j = 0; j < 8; ++j) fb[j] = 0.5 * (double)XB[a * 132 + C0 + j];
      #pragma unroll
      for (int i = 0; i < 8; ++i)
        #pragma unroll
        for (int j = 0; j < 8; ++j) g[i][j] += fa[i] * fb[j];
    }
    __syncthreads();
  }
  for (int p = 0; p < 128; ++p) {
    int pb = p >> 3, pl = p & 7;
    if (ti == pb) {
      #pragma unroll
      for (int j = 0; j < 8; ++j) prow[C0 + j] = g[pl][j];
    }
    if (tj == pb) {
      #pragma unroll
      for (int i = 0; i < 8; ++i) fcol[R0 + i] = g[i][pl];
    }
    __syncthreads();
    double d = 1.0 / prow[p];
    double pd[8];
    #pragma unroll
    for (int j = 0; j < 8; ++j) pd[j] = prow[C0 + j] * d;
    #pragma unroll
    for (int i = 0; i < 8; ++i) {
      int r = R0 + i;
      if (r == p) {
        #pragma unroll
        for (int j = 0; j < 8; ++j) g[i][j] = ((C0 + j) == p) ? d : pd[j];
      } else {
        double f = fcol[r];
        #pragma unroll
        for (int j = 0; j < 8; ++j)
          g[i][j] = ((C0 + j) == p) ? (-f * d) : (g[i][j] - f * pd[j]);
      }
    }
    __syncthreads();
  }
  TR* Ys = Yscr + (size_t)site * 16384;
  TT* Ts = Tk + (size_t)site * 32768;
  #pragma unroll
  for (int i = 0; i < 8; ++i) {
    int r = R0 + i, s = r & 1, a = r >> 1;
    #pragma unroll
    for (int j = 0; j < 8; ++j) {
      int c = C0 + j;
      Ys[(size_t)r * 128 + c] = (TR)g[i][j];
      Ts[((size_t)s * 128 + a) * 128 + c] =
          (TT)(2.0 * g[i][j] - ((r == c) ? 1.0 : 0.0));
    }
  }
}

// ---------------------------------------------------------------- W_bot = -X2 * Y
template <typename TT, typename TR>
__global__ __launch_bounds__(256) void k_w2(const float* __restrict__ params,
                                            const TR* __restrict__ Yscr,
                                            TT* __restrict__ Tk) {
  __shared__ float X2c[16 * 132];
  __shared__ double Yt[16 * 130];
  const int site = blockIdx.x, tid = threadIdx.x;
  const float* X2g = params + (size_t)site * 256 * 128 + 128 * 128;
  const TR* Ys = Yscr + (size_t)site * 16384;
  TT* Ts = Tk + (size_t)site * 32768;
  const int ti = tid >> 4, tj = tid & 15;
  const int R0 = ti * 8, C0 = tj * 8;
  double acc[8][8];
  #pragma unroll
  for (int i = 0; i < 8; ++i)
    #pragma unroll
    for (int j = 0; j < 8; ++j) acc[i][j] = 0.0;
  for (int b0 = 0; b0 < 128; b0 += 16) {
    __syncthreads();
    for (int idx = tid; idx < 2048; idx += 256) {
      int r = idx >> 4, bb = idx & 15;
      X2c[bb * 132 + r] = X2g[(size_t)r * 128 + b0 + bb];
    }
    for (int idx = tid; idx < 2048; idx += 256) {
      int bb = idx >> 7, c = idx & 127;
      Yt[bb * 130 + c] = (double)Ys[(size_t)(b0 + bb) * 128 + c];
    }
    __syncthreads();
    for (int bb = 0; bb < 16; ++bb) {
      double xf[8], yf[8];
      #pragma unroll
      for (int i = 0; i < 8; ++i) xf[i] = (double)X2c[bb * 132 + R0 + i];
      #pragma unroll
      for (int j = 0; j < 8; ++j) yf[j] = Yt[bb * 130 + C0 + j];
      #pragma unroll
      for (int i = 0; i < 8; ++i)
        #pragma unroll
        for (int j = 0; j < 8; ++j) acc[i][j] += xf[i] * yf[j];
    }
  }
  #pragma unroll
  for (int i = 0; i < 8; ++i) {
    int r = 128 + R0 + i, s = r & 1, a = r >> 1;
    #pragma unroll
    for (int j = 0; j < 8; ++j)
      Ts[((size_t)s * 128 + a) * 128 + C0 + j] = (TT)(-acc[i][j]);
  }
}

// ---------------------------------------------------------------- fence-free sync
// Versioned counters (one 32-int block per sync point, zeroed by k_init).
// 16 sub-counters (base[w&15], 16 WGs each) + root (base[16]). Relaxed agent
// atomics only: data moves via write-through atomics, so NO agent fences
// (avoids buffer_wbl2 / buffer_inv L2 storms -- the round-2 82.8ms pathology).
// Ordering: compiler emits s_waitcnt vmcnt(0) before s_barrier (m97), so all
// waves' atomic stores are at the coherence point before tid0 arrives.
__device__ __forceinline__ void garrive(int* base, int w, int tid) {
  __syncthreads();
  if (tid == 0) {
    __builtin_amdgcn_s_waitcnt(0);
    int old = __hip_atomic_fetch_add(base + (w & 15), 1, __ATOMIC_RELAXED,
                                     __HIP_MEMORY_SCOPE_AGENT);
    if (old == 15)
      __hip_atomic_fetch_add(base + 16, 1, __ATOMIC_RELAXED,
                             __HIP_MEMORY_SCOPE_AGENT);
  }
}
__device__ __forceinline__ void gwait(int* base, int tid) {
  if (tid == 0) {
    while (__hip_atomic_load(base + 16, __ATOMIC_RELAXED,
                             __HIP_MEMORY_SCOPE_AGENT) < 16)
      __builtin_amdgcn_s_sleep(1);
  }
  __syncthreads();
}

// ---------------------------------------------------------------- reverse scan
// step i: P[(j,a)][b] = sum_d K[(j,a)][d] Rin[d][b];
//         Rout[a][c]  = sum_{j,b} P[(j,a)][b] K[(j,c)][b]
// 256 WGs: stage A tile = 16 P-rows x 8 cols; stage B tile = 8 x 8.
template <typename TT, typename TR>
__global__ __launch_bounds__(256) void k_scan(const TT* __restrict__ Tk,
                                              TR* __restrict__ Rbuf,
                                              double* __restrict__ Pscr,
                                              TR* __restrict__ Rs0,
                                              double* __restrict__ Zp,
                                              int* __restrict__ bars) {
  __shared__ double buf1[16 * 129];  // A: KA rows   | B: P rows
  __shared__ double buf2[8 * 129];   // A: RinT cols
  __shared__ double buf3[16 * 129];  // B: K c-rows (prefetched)
  __shared__ double red[256];
  const int w = blockIdx.x, tid = threadIdx.x;
  const int grpA = w >> 4, bt = w & 15;
  const int a0 = (w >> 4) * 8, c0 = (w & 15) * 8;
  // preload first KA tile
  {
    const TT* K = Tk + (size_t)(NS - 1) * 32768;
    for (int idx = tid; idx < 2048; idx += 256) {
      int rr = idx >> 7, d = idx & 127;
      buf1[rr * 129 + d] = (double)K[(size_t)(grpA * 16 + rr) * 128 + d];
    }
  }
  for (int i = NS - 1; i >= 0; --i) {
    const TT* K = Tk + (size_t)i * 32768;
    const TR* Rin = Rbuf + (size_t)i * 16384;
    int* c1 = bars + (size_t)((NS - 1 - i) * 2) * 32;
    int* c2 = c1 + 32;
    // ---- stage A: load RinT (atomic; written by other WGs last step) ----
    for (int idx = tid; idx < 1024; idx += 256) {
      int d = idx >> 3, bb = idx & 7;
      buf2[bb * 129 + d] = (double)aldT(&Rin[(size_t)d * 128 + bt * 8 + bb]);
    }
    __syncthreads();
    {
      int h = tid >> 7, rr = (tid >> 3) & 15, bb = tid & 7;
      const double* ka = buf1 + rr * 129 + h * 64;
      const double* rb = buf2 + bb * 129 + h * 64;
      double s0 = 0, s1 = 0, s2 = 0, s3 = 0;
      #pragma unroll
      for (int d = 0; d < 64; d += 4) {
        s0 += ka[d] * rb[d];     s1 += ka[d + 1] * rb[d + 1];
        s2 += ka[d + 2] * rb[d + 2]; s3 += ka[d + 3] * rb[d + 3];
      }
      red[tid] = (s0 + s1) + (s2 + s3);
    }
    __syncthreads();
    if (tid < 128) {
      int rr = tid >> 3, bb = tid & 7;
      ast(&Pscr[(size_t)(grpA * 16 + rr) * 128 + bt * 8 + bb],
          red[tid] + red[tid + 128]);
    }
    garrive(c1, w, tid);
    // prefetch stage-B K rows (independent of P) while sync-1 settles
    for (int idx = tid; idx < 2048; idx += 256) {
      int row = idx >> 7, e = idx & 127;
      int j = row >> 3, cc = row & 7;
      buf3[row * 129 + e] = (double)K[(size_t)(j * 128 + c0 + cc) * 128 + e];
    }
    gwait(c1, tid);
    // ---- stage B: load P rows (atomic) ----
    for (int idx = tid; idx < 2048; idx += 256) {
      int row = idx >> 7, e = idx & 127;
      int j = row >> 3, aa = row & 7;
      buf1[row * 129 + e] = ald(&Pscr[(size_t)(j * 128 + a0 + aa) * 128 + e]);
    }
    __syncthreads();
    {
      int j = tid >> 7, h = (tid >> 6) & 1, aa = (tid >> 3) & 7, cc = tid & 7;
      const double* pa = buf1 + (j * 8 + aa) * 129 + h * 64;
      const double* kb = buf3 + (j * 8 + cc) * 129 + h * 64;
      double s0 = 0, s1 = 0, s2 = 0, s3 = 0;
      #pragma unroll
      for (int e = 0; e < 64; e += 4) {
        s0 += pa[e] * kb[e];     s1 += pa[e + 1] * kb[e + 1];
        s2 += pa[e + 2] * kb[e + 2]; s3 += pa[e + 3] * kb[e + 3];
      }
      red[tid] = (s0 + s1) + (s2 + s3);
    }
    __syncthreads();
    if (tid < 64) {
      int aa = tid >> 3, cc = tid & 7;
      double s = red[tid] + red[tid + 64] + red[tid + 128] + red[tid + 192];
      TR* outp = (i > 0) ? (Rbuf + (size_t)(i - 1) * 16384) : Rs0;
      ast(&outp[(size_t)(a0 + aa) * 128 + c0 + cc], (TR)s);
      if (i == 0 && w == 0 && tid == 0) ast(Zp, s);
    }
    garrive(c2, w, tid);
    // preload next step's KA (local to this WG) while sync-2 settles
    if (i > 0) {
      const TT* Kn = Tk + (size_t)(i - 1) * 32768;
      for (int idx = tid; idx < 2048; idx += 256) {
        int rr = idx >> 7, d = idx & 127;
        buf1[rr * 129 + d] = (double)Kn[(size_t)(grpA * 16 + rr) * 128 + d];
      }
    }
    gwait(c2, tid);
  }
}

// ---------------------------------------------------------------- sampling sweep
// L = w w^T rank-1: y_s = T_s^T w ; ps0 = y1^T R y1 (site0: /Z);
// w' = y_k / sqrt(p * (site0 ? Z : 1)). v computed as per-thread partials of the
// full quadratic form -> ONE butterfly + 16-elem LDS reduce (critical path).
template <typename TT, typename TR>
__global__ __launch_bounds__(1024) void k_sample(const TT* __restrict__ Tk,
                                                 const TR* __restrict__ Rbuf,
                                                 double* __restrict__ wbuf,
                                                 const double* __restrict__ Zp,
                                                 const float* __restrict__ randu,
                                                 float* __restrict__ out) {
  __shared__ double wl[128], yl[256], part[1024], ctrl[2];
  const int g = blockIdx.x, tid = threadIdx.x;
  const int s = tid >> 9, q = (tid >> 7) & 3, b = tid & 127;
  const int lane = tid & 63, wv = tid >> 6;
  using TR2 = typename V2<TR>::t;
  for (int site = g; site < NS; site += 16) {
    const TT* T = Tk + (size_t)site * 32768;
    double tf[32];
    {
      const TT* tp = T + ((size_t)s * 128 + q * 32) * 128 + b;
      #pragma unroll
      for (int t = 0; t < 32; ++t) tf[t] = (double)tp[(size_t)t * 128];
    }
    double rv[16];  // R rows 16t+wv, cols 2*lane, 2*lane+1
    {
      const TR2* R2 = (const TR2*)(Rbuf + (size_t)site * 16384);
      #pragma unroll
      for (int t = 0; t < 8; ++t) {
        TR2 v = R2[t * 1024 + tid];
        rv[2 * t] = (double)v.x; rv[2 * t + 1] = (double)v.y;
      }
    }
    if (tid < 128) {  // poll w (payload-is-flag)
      double* wp = wbuf + (size_t)site * 128 + tid;
      double v;
      do { v = ald(wp); } while (v == SENT);
      wl[tid] = v;
    }
    __syncthreads();
    {  // y_s[b] partials over a-quarter
      double p0 = 0.0;
      #pragma unroll
      for (int t = 0; t < 32; ++t) p0 += tf[t] * wl[q * 32 + t];
      part[(s * 4 + q) * 128 + b] = p0;
    }
    __syncthreads();
    if (tid < 256) {
      int ss = tid >> 7, bb = tid & 127;
      yl[ss * 128 + bb] = part[(ss * 4) * 128 + bb] + part[(ss * 4 + 1) * 128 + bb] +
                          part[(ss * 4 + 2) * 128 + bb] + part[(ss * 4 + 3) * 128 + bb];
    }
    __syncthreads();
    {  // v = y1^T R y1: per-thread 8 rows x 2 cols, one butterfly
      double y1a = yl[128 + 2 * lane], y1b = yl[128 + 2 * lane + 1];
      double vp = 0.0;
      #pragma unroll
      for (int t = 0; t < 8; ++t)
        vp += yl[128 + 16 * t + wv] * (rv[2 * t] * y1a + rv[2 * t + 1] * y1b);
      #pragma unroll
      for (int off = 1; off < 64; off <<= 1) vp += __shfl_xor(vp, off, 64);
      if (lane == 0) part[wv] = vp;
    }
    __syncthreads();
    if (tid == 0) {
      double v = 0.0;
      #pragma unroll
      for (int k = 0; k < 16; ++k) v += part[k];
      double zn = (site == 0) ? *Zp : 1.0;
      double ps0 = v / zn;
      double u = (double)randu[site];
      bool take0 = u < ps0;
      double pp = take0 ? ps0 : (1.0 - ps0);
      ctrl[0] = take0 ? 1.0 : 0.0;
      ctrl[1] = 1.0 / sqrt(pp * zn);   // site0: w' = y_k/sqrt(p_u), p_u = pp*Z
      out[2 * site] = take0 ? 0.0f : 1.0f;
      out[2 * site + 1] = take0 ? 1.0f : 0.0f;
    }
    __syncthreads();
    {
      int k = (ctrl[0] != 0.0) ? 1 : 0;
      double sc = ctrl[1];
      if (tid < 128)
        ast(&wbuf[(size_t)(site + 1) * 128 + tid], yl[k * 128 + tid] * sc);
    }
    __syncthreads();
  }
}

// ---------------------------------------------------------------- diagnostics
__global__ void k_diag(float* __restrict__ out, int n, float mb) {
  int i = blockIdx.x * blockDim.x + threadIdx.x;
  if (i < n) out[i] = (i == 0) ? mb : ((i & 1) ? 0.75f : 0.25f);
}

// ---------------------------------------------------------------- launch
template <typename TT, typename TR>
struct Plan {
  size_t oTk, oR, oRs0, oP, oW, oB, oZ, need;
  Plan() {
    oTk = 0;
    oR = oTk + sizeof(TT) * (size_t)NS * 32768;
    oRs0 = oR + sizeof(TR) * (size_t)NS * 16384;   // Rbuf; also aliases Yscr
    oP = oRs0 + sizeof(TR) * 16384;
    oW = oP + 8ull * 256 * 128;
    oB = oW + 8ull * (NS + 1) * 128;
    oZ = oB + 4ull * 2048 * 32;
    need = oZ + 64;
  }
};

template <typename TT, typename TR>
static void run_cfg(const float* params, const float* randu, float* out,
                    char* ws, hipStream_t stream) {
  Plan<TT, TR> P;
  TT* Tk = (TT*)(ws + P.oTk);
  TR* Rbuf = (TR*)(ws + P.oR);
  TR* Yscr = Rbuf;  // Y consumed by k_w2 before k_init/k_scan touch Rbuf
  TR* Rs0 = (TR*)(ws + P.oRs0);
  double* Pscr = (double*)(ws + P.oP);
  double* wbuf = (double*)(ws + P.oW);
  int* bars = (int*)(ws + P.oB);
  double* Zp = (double*)(ws + P.oZ);
  k_cayley<TT, TR><<<dim3(NS), dim3(256), 0, stream>>>(params, Tk, Yscr);
  k_w2<TT, TR><<<dim3(NS), dim3(256), 0, stream>>>(params, Yscr, Tk);
  k_init<TR><<<dim3(256), dim3(256), 0, stream>>>(
      wbuf, Rbuf + (size_t)(NS - 1) * 16384, bars, 2048 * 32);
  k_scan<TT, TR><<<dim3(256), dim3(256), 0, stream>>>(Tk, Rbuf, Pscr, Rs0, Zp, bars);
  k_sample<TT, TR><<<dim3(16), dim3(1024), 0, stream>>>(Tk, Rbuf, wbuf, Zp, randu, out);
}

extern "C" void kernel_launch(void* const* d_in, const int* in_sizes, int n_in,
                              void* d_out, int out_size, void* d_ws, size_t ws_size,
                              hipStream_t stream) {
  const float* params = (const float*)d_in[0];
  const float* randu = (const float*)d_in[1];
  float* out = (float*)d_out;
  char* ws = (char*)d_ws;
  if (ws_size >= Plan<double, double>().need) {
    run_cfg<double, double>(params, randu, out, ws, stream);
  } else if (ws_size >= Plan<float, double>().need) {
    run_cfg<float, double>(params, randu, out, ws, stream);
  } else if (ws_size >= Plan<float, float>().need) {
    run_cfg<float, float>(params, randu, out, ws, stream);
  } else {
    k_diag<<<dim3((out_size + 255) / 256), dim3(256), 0, stream>>>(
        out, out_size, (float)(ws_size >> 20));
  }
}

// Round 4
// 16991.878 us; speedup vs baseline: 5.6343x; 1.2756x over previous
//
#include <hip/hip_runtime.h>
#include <math.h>

#define NS 1024
#define SENT (-1.0e300)

template <typename T> struct V2;
template <> struct V2<double> { using t = double2; };
template <> struct V2<float>  { using t = float2; };

template <typename T> __device__ __forceinline__ T sentv();
template <> __device__ __forceinline__ double sentv<double>() { return -1.0e300; }
template <> __device__ __forceinline__ float  sentv<float>()  { return -3.0e38f; }

template <typename T>
__device__ __forceinline__ T aldT(const T* p) {
  return __hip_atomic_load(p, __ATOMIC_RELAXED, __HIP_MEMORY_SCOPE_AGENT);
}
__device__ __forceinline__ double ald(const double* p) {
  return __hip_atomic_load(p, __ATOMIC_RELAXED, __HIP_MEMORY_SCOPE_AGENT);
}
template <typename T>
__device__ __forceinline__ void ast(T* p, T v) {
  __hip_atomic_store(p, v, __ATOMIC_RELAXED, __HIP_MEMORY_SCOPE_AGENT);
}

// ---------------------------------------------------------------- init
// wbuf: ring handoff for k_sample (sentinel-poisoned). Rbuf: slots 0..NS-2
// sentinel-poisoned (each written exactly once by k_scan), slot NS-1 = outer(r,r).
template <typename TR>
__global__ void k_init(double* __restrict__ wbuf, TR* __restrict__ Rbuf) {
  size_t stride = (size_t)gridDim.x * blockDim.x;
  size_t t = (size_t)blockIdx.x * blockDim.x + threadIdx.x;
  for (size_t idx = t; idx < (size_t)(NS + 1) * 128; idx += stride)
    wbuf[idx] = (idx < 128) ? ((idx == 0) ? 1.0 : 0.0) : SENT;
  const size_t lastoff = (size_t)(NS - 1) * 16384;
  for (size_t idx = t; idx < (size_t)NS * 16384; idx += stride)
    Rbuf[idx] = (idx < lastoff) ? sentv<TR>()
                                : (TR)((idx == lastoff) ? 1.0f : 0.0f);
}

// ---------------------------------------------------------------- cayley
// G = I + 0.5(X1-X1^T) + 0.25 X2^T X2 ; Y = G^{-1} (pivot-free GJ; sym(G)>=I).
// W_top = 2Y - I -> Tk ; Y -> Yscr (aliases Rbuf, consumed by k_w2 before k_init).
template <typename TT, typename TR>
__global__ __launch_bounds__(256) void k_cayley(const float* __restrict__ params,
                                                TT* __restrict__ Tk,
                                                TR* __restrict__ Yscr) {
  __shared__ float XB[64 * 132];
  __shared__ double prow[128], fcol[128];
  const int site = blockIdx.x, tid = threadIdx.x;
  const float* X = params + (size_t)site * 256 * 128;
  const int ti = tid >> 4, tj = tid & 15;
  const int R0 = ti * 8, C0 = tj * 8;
  double g[8][8];
  #pragma unroll
  for (int i = 0; i < 8; ++i)
    #pragma unroll
    for (int j = 0; j < 8; ++j) g[i][j] = ((R0 + i) == (C0 + j)) ? 1.0 : 0.0;
  for (int h = 0; h < 2; ++h) {
    for (int idx = tid; idx < 64 * 128; idx += 256) {
      int rr = idx >> 7, c = idx & 127;
      XB[rr * 132 + c] = X[(size_t)(h * 64 + rr) * 128 + c];
    }
    __syncthreads();
    int lo = h * 64;
    if ((R0 >> 6) == h) {
      #pragma unroll
      for (int i = 0; i < 8; ++i)
        #pragma unroll
        for (int j = 0; j < 8; ++j)
          g[i][j] += 0.5 * (double)XB[(R0 + i - lo) * 132 + (C0 + j)];
    }
    if ((C0 >> 6) == h) {
      #pragma unroll
      for (int i = 0; i < 8; ++i)
        #pragma unroll
        for (int j = 0; j < 8; ++j)
          g[i][j] -= 0.5 * (double)XB[(C0 + j - lo) * 132 + (R0 + i)];
    }
    __syncthreads();
  }
  for (int h = 0; h < 2; ++h) {
    for (int idx = tid; idx < 64 * 128; idx += 256) {
      int rr = idx >> 7, c = idx & 127;
      XB[rr * 132 + c] = X[(size_t)(128 + h * 64 + rr) * 128 + c];
    }
    __syncthreads();
    for (int a = 0; a < 64; ++a) {
      double fa[8], fb[8];
      #pragma unroll
      for (int i = 0; i < 8; ++i) fa[i] = 0.5 * (double)XB[a * 132 + R0 + i];
      #pragma unroll
      for (int j = 0; j < 8; ++j) fb[j] = 0.5 * (double)XB[a * 132 + C0 + j];
      #pragma unroll
      for (int i = 0; i < 8; ++i)
        #pragma unroll
        for (int j = 0; j < 8; ++j) g[i][j] += fa[i] * fb[j];
    }
    __syncthreads();
  }
  for (int p = 0; p < 128; ++p) {
    int pb = p >> 3, pl = p & 7;
    if (ti == pb) {
      #pragma unroll
      for (int j = 0; j < 8; ++j) prow[C0 + j] = g[pl][j];
    }
    if (tj == pb) {
      #pragma unroll
      for (int i = 0; i < 8; ++i) fcol[R0 + i] = g[i][pl];
    }
    __syncthreads();
    double d = 1.0 / prow[p];
    double pd[8];
    #pragma unroll
    for (int j = 0; j < 8; ++j) pd[j] = prow[C0 + j] * d;
    #pragma unroll
    for (int i = 0; i < 8; ++i) {
      int r = R0 + i;
      if (r == p) {
        #pragma unroll
        for (int j = 0; j < 8; ++j) g[i][j] = ((C0 + j) == p) ? d : pd[j];
      } else {
        double f = fcol[r];
        #pragma unroll
        for (int j = 0; j < 8; ++j)
          g[i][j] = ((C0 + j) == p) ? (-f * d) : (g[i][j] - f * pd[j]);
      }
    }
    __syncthreads();
  }
  TR* Ys = Yscr + (size_t)site * 16384;
  TT* Ts = Tk + (size_t)site * 32768;
  #pragma unroll
  for (int i = 0; i < 8; ++i) {
    int r = R0 + i, s = r & 1, a = r >> 1;
    #pragma unroll
    for (int j = 0; j < 8; ++j) {
      int c = C0 + j;
      Ys[(size_t)r * 128 + c] = (TR)g[i][j];
      Ts[((size_t)s * 128 + a) * 128 + c] =
          (TT)(2.0 * g[i][j] - ((r == c) ? 1.0 : 0.0));
    }
  }
}

// ---------------------------------------------------------------- W_bot = -X2 * Y
template <typename TT, typename TR>
__global__ __launch_bounds__(256) void k_w2(const float* __restrict__ params,
                                            const TR* __restrict__ Yscr,
                                            TT* __restrict__ Tk) {
  __shared__ float X2c[16 * 132];
  __shared__ double Yt[16 * 130];
  const int site = blockIdx.x, tid = threadIdx.x;
  const float* X2g = params + (size_t)site * 256 * 128 + 128 * 128;
  const TR* Ys = Yscr + (size_t)site * 16384;
  TT* Ts = Tk + (size_t)site * 32768;
  const int ti = tid >> 4, tj = tid & 15;
  const int R0 = ti * 8, C0 = tj * 8;
  double acc[8][8];
  #pragma unroll
  for (int i = 0; i < 8; ++i)
    #pragma unroll
    for (int j = 0; j < 8; ++j) acc[i][j] = 0.0;
  for (int b0 = 0; b0 < 128; b0 += 16) {
    __syncthreads();
    for (int idx = tid; idx < 2048; idx += 256) {
      int r = idx >> 4, bb = idx & 15;
      X2c[bb * 132 + r] = X2g[(size_t)r * 128 + b0 + bb];
    }
    for (int idx = tid; idx < 2048; idx += 256) {
      int bb = idx >> 7, c = idx & 127;
      Yt[bb * 130 + c] = (double)Ys[(size_t)(b0 + bb) * 128 + c];
    }
    __syncthreads();
    for (int bb = 0; bb < 16; ++bb) {
      double xf[8], yf[8];
      #pragma unroll
      for (int i = 0; i < 8; ++i) xf[i] = (double)X2c[bb * 132 + R0 + i];
      #pragma unroll
      for (int j = 0; j < 8; ++j) yf[j] = Yt[bb * 130 + C0 + j];
      #pragma unroll
      for (int i = 0; i < 8; ++i)
        #pragma unroll
        for (int j = 0; j < 8; ++j) acc[i][j] += xf[i] * yf[j];
    }
  }
  #pragma unroll
  for (int i = 0; i < 8; ++i) {
    int r = 128 + R0 + i, s = r & 1, a = r >> 1;
    #pragma unroll
    for (int j = 0; j < 8; ++j)
      Ts[((size_t)s * 128 + a) * 128 + C0 + j] = (TT)(-acc[i][j]);
  }
}

// ---------------------------------------------------------------- reverse scan
// BARRIER-FREE: each Rbuf slot is written exactly once (slot = site), poisoned
// by k_init; consumers sentinel-poll the payload (the proven k_sample pattern).
// Each WG computes its 4x16 output tile SELF-SUFFICIENTLY:
//   stage A (local): P[8rows(j,aa)][128b] = KA(8x128) * R(128x128)  (R streamed
//     in 16-row chunks via relaxed atomic loads w/ per-thread SENT spin)
//   stage B (local): R'[a0+aa][c0+cc] = sum_{j,b} P[(j,aa)][b]*KC[(j,cc)][b]
// Grid 256 WGs x 512 thr (a-tiles 32 x c-tiles 8). No Pscr, no counters.
template <typename TT, typename TR>
__global__ __launch_bounds__(512) void k_scan(const TT* __restrict__ Tk,
                                              TR* __restrict__ Rbuf,
                                              TR* __restrict__ Rs0,
                                              double* __restrict__ Zp) {
  __shared__ double KA[8 * 128];    // rows (j,aa): row = j*4+aa
  __shared__ double KC[16 * 129];   // one j-half of the 32 c-rows
  __shared__ double Rt[16 * 128];   // 16-d-row chunk of R
  __shared__ double Pb[8 * 129];    // stage-A output
  __shared__ double red[256];
  const int w = blockIdx.x, tid = threadIdx.x;
  const int a0 = (w >> 3) * 4, c0 = (w & 7) * 16;
  const int r2 = tid >> 7, bh = tid & 127;   // stage-A: rows {r2, r2+4}, col bh
  const TR SV = sentv<TR>();
  for (int i = NS - 1; i >= 0; --i) {
    const TT* K = Tk + (size_t)i * 32768;
    const TR* Rin = Rbuf + (size_t)i * 16384;
    // prefetch chunk 0 (atomic; bypasses stale L2)
    double v[4];
    #pragma unroll
    for (int u = 0; u < 4; ++u) {
      TR t = aldT(Rin + tid * 4 + u);
      v[u] = (t == SV) ? SENT : (double)t;
    }
    // KA -> LDS (plain loads; K is read-only, written pre-kernel)
    for (int idx = tid; idx < 1024; idx += 512) {
      int row = idx >> 7, col = idx & 127;
      KA[idx] = (double)K[(size_t)((row >> 2) * 128 + a0 + (row & 3)) * 128 + col];
    }
    // KC (32 rows) -> registers; dumped to LDS per j-half in stage B
    double kc[8];
    #pragma unroll
    for (int u = 0; u < 8; ++u) {
      int row = r2 + 4 * u;   // (tid + u*512)>>7
      kc[u] = (double)K[(size_t)((row >> 4) * 128 + c0 + (row & 15)) * 128 + bh];
    }
    double acc0 = 0.0, acc1 = 0.0;
    for (int c = 0; c < 8; ++c) {
      // validate chunk c (per-thread spin; no WG consensus needed)
      while (v[0] == SENT || v[1] == SENT || v[2] == SENT || v[3] == SENT) {
        __builtin_amdgcn_s_sleep(1);
        #pragma unroll
        for (int u = 0; u < 4; ++u)
          if (v[u] == SENT) {
            TR t = aldT(Rin + c * 2048 + tid * 4 + u);
            v[u] = (t == SV) ? SENT : (double)t;
          }
      }
      {
        int base = tid * 4, dl = base >> 7, bb = base & 127;
        Rt[dl * 128 + bb] = v[0];
        Rt[dl * 128 + bb + 1] = v[1];
        Rt[dl * 128 + bb + 2] = v[2];
        Rt[dl * 128 + bb + 3] = v[3];
      }
      __syncthreads();
      if (c < 7) {   // prefetch chunk c+1; latency hidden by compute below
        #pragma unroll
        for (int u = 0; u < 4; ++u) {
          TR t = aldT(Rin + (c + 1) * 2048 + tid * 4 + u);
          v[u] = (t == SV) ? SENT : (double)t;
        }
      }
      #pragma unroll
      for (int dl = 0; dl < 16; ++dl) {
        int d = c * 16 + dl;
        double rr = Rt[dl * 128 + bh];
        acc0 += KA[r2 * 128 + d] * rr;
        acc1 += KA[(r2 + 4) * 128 + d] * rr;
      }
      __syncthreads();
    }
    Pb[r2 * 129 + bh] = acc0;
    Pb[(r2 + 4) * 129 + bh] = acc1;
    __syncthreads();
    // stage B: two j passes through the 16-row KC buffer
    double s = 0.0;
    const int oi = tid & 63, seg = (tid >> 6) & 3;
    #pragma unroll
    for (int j = 0; j < 2; ++j) {
      #pragma unroll
      for (int t = 0; t < 4; ++t)
        KC[(r2 + 4 * t) * 129 + bh] = kc[j * 4 + t];
      __syncthreads();
      if (tid < 256) {
        int aa = oi >> 4, cc = oi & 15;
        double acc = 0.0;
        #pragma unroll
        for (int m = 0; m < 32; ++m) {
          int b = seg * 32 + m;
          acc += Pb[(j * 4 + aa) * 129 + b] * KC[cc * 129 + b];
        }
        s += acc;
      }
      __syncthreads();
    }
    if (tid < 256) red[tid] = s;
    __syncthreads();
    if (tid < 64) {
      int aa = tid >> 4, cc = tid & 15;
      double o = red[tid] + red[tid + 64] + red[tid + 128] + red[tid + 192];
      TR* outp = (i > 0) ? (Rbuf + (size_t)(i - 1) * 16384) : Rs0;
      ast(&outp[(size_t)(a0 + aa) * 128 + c0 + cc], (TR)o);
      if (i == 0 && w == 0 && tid == 0) ast(Zp, o);
    }
    __syncthreads();   // protect red/KC/KA/Rt before next step's overwrites
  }
}

// ---------------------------------------------------------------- sampling sweep
// L = w w^T rank-1: y_s = T_s^T w ; ps0 = y1^T R y1 (site0: /Z);
// w' = y_k / sqrt(p * (site0 ? Z : 1)). w handed WG->WG via sentinel poll.
template <typename TT, typename TR>
__global__ __launch_bounds__(1024) void k_sample(const TT* __restrict__ Tk,
                                                 const TR* __restrict__ Rbuf,
                                                 double* __restrict__ wbuf,
                                                 const double* __restrict__ Zp,
                                                 const float* __restrict__ randu,
                                                 float* __restrict__ out) {
  __shared__ double wl[128], yl[256], part[1024], ctrl[2];
  const int g = blockIdx.x, tid = threadIdx.x;
  const int s = tid >> 9, q = (tid >> 7) & 3, b = tid & 127;
  const int lane = tid & 63, wv = tid >> 6;
  using TR2 = typename V2<TR>::t;
  for (int site = g; site < NS; site += 16) {
    const TT* T = Tk + (size_t)site * 32768;
    double tf[32];
    {
      const TT* tp = T + ((size_t)s * 128 + q * 32) * 128 + b;
      #pragma unroll
      for (int t = 0; t < 32; ++t) tf[t] = (double)tp[(size_t)t * 128];
    }
    double rv[16];  // R rows 16t+wv, cols 2*lane, 2*lane+1
    {
      const TR2* R2 = (const TR2*)(Rbuf + (size_t)site * 16384);
      #pragma unroll
      for (int t = 0; t < 8; ++t) {
        TR2 v = R2[t * 1024 + tid];
        rv[2 * t] = (double)v.x; rv[2 * t + 1] = (double)v.y;
      }
    }
    if (tid < 128) {  // poll w (payload-is-flag) with backoff
      double* wp = wbuf + (size_t)site * 128 + tid;
      double v;
      while ((v = ald(wp)) == SENT) __builtin_amdgcn_s_sleep(1);
      wl[tid] = v;
    }
    __syncthreads();
    {  // y_s[b] partials over a-quarter
      double p0 = 0.0;
      #pragma unroll
      for (int t = 0; t < 32; ++t) p0 += tf[t] * wl[q * 32 + t];
      part[(s * 4 + q) * 128 + b] = p0;
    }
    __syncthreads();
    if (tid < 256) {
      int ss = tid >> 7, bb = tid & 127;
      yl[ss * 128 + bb] = part[(ss * 4) * 128 + bb] + part[(ss * 4 + 1) * 128 + bb] +
                          part[(ss * 4 + 2) * 128 + bb] + part[(ss * 4 + 3) * 128 + bb];
    }
    __syncthreads();
    {  // v = y1^T R y1: per-thread 8 rows x 2 cols, one butterfly
      double y1a = yl[128 + 2 * lane], y1b = yl[128 + 2 * lane + 1];
      double vp = 0.0;
      #pragma unroll
      for (int t = 0; t < 8; ++t)
        vp += yl[128 + 16 * t + wv] * (rv[2 * t] * y1a + rv[2 * t + 1] * y1b);
      #pragma unroll
      for (int off = 1; off < 64; off <<= 1) vp += __shfl_xor(vp, off, 64);
      if (lane == 0) part[wv] = vp;
    }
    __syncthreads();
    if (tid == 0) {
      double v = 0.0;
      #pragma unroll
      for (int k = 0; k < 16; ++k) v += part[k];
      double zn = (site == 0) ? *Zp : 1.0;
      double ps0 = v / zn;
      double u = (double)randu[site];
      bool take0 = u < ps0;
      double pp = take0 ? ps0 : (1.0 - ps0);
      ctrl[0] = take0 ? 1.0 : 0.0;
      ctrl[1] = 1.0 / sqrt(pp * zn);   // site0: w' = y_k/sqrt(p_u), p_u = pp*Z
      out[2 * site] = take0 ? 0.0f : 1.0f;
      out[2 * site + 1] = take0 ? 1.0f : 0.0f;
    }
    __syncthreads();
    {
      int k = (ctrl[0] != 0.0) ? 1 : 0;
      double sc = ctrl[1];
      if (tid < 128)
        ast(&wbuf[(size_t)(site + 1) * 128 + tid], yl[k * 128 + tid] * sc);
    }
    __syncthreads();
  }
}

// ---------------------------------------------------------------- diagnostics
__global__ void k_diag(float* __restrict__ out, int n, float mb) {
  int i = blockIdx.x * blockDim.x + threadIdx.x;
  if (i < n) out[i] = (i == 0) ? mb : ((i & 1) ? 0.75f : 0.25f);
}

// ---------------------------------------------------------------- launch
template <typename TT, typename TR>
struct Plan {
  size_t oTk, oR, oRs0, oW, oZ, need;
  Plan() {
    oTk = 0;
    oR = oTk + sizeof(TT) * (size_t)NS * 32768;
    oRs0 = oR + sizeof(TR) * (size_t)NS * 16384;   // Rbuf; also aliases Yscr
    oW = oRs0 + sizeof(TR) * 16384;
    oZ = oW + 8ull * (NS + 1) * 128;
    need = oZ + 64;
  }
};

template <typename TT, typename TR>
static void run_cfg(const float* params, const float* randu, float* out,
                    char* ws, hipStream_t stream) {
  Plan<TT, TR> P;
  TT* Tk = (TT*)(ws + P.oTk);
  TR* Rbuf = (TR*)(ws + P.oR);
  TR* Yscr = Rbuf;  // Y consumed by k_w2 before k_init poisons Rbuf
  TR* Rs0 = (TR*)(ws + P.oRs0);
  double* wbuf = (double*)(ws + P.oW);
  double* Zp = (double*)(ws + P.oZ);
  k_cayley<TT, TR><<<dim3(NS), dim3(256), 0, stream>>>(params, Tk, Yscr);
  k_w2<TT, TR><<<dim3(NS), dim3(256), 0, stream>>>(params, Yscr, Tk);
  k_init<TR><<<dim3(4096), dim3(256), 0, stream>>>(wbuf, Rbuf);
  k_scan<TT, TR><<<dim3(256), dim3(512), 0, stream>>>(Tk, Rbuf, Rs0, Zp);
  k_sample<TT, TR><<<dim3(16), dim3(1024), 0, stream>>>(Tk, Rbuf, wbuf, Zp, randu, out);
}

extern "C" void kernel_launch(void* const* d_in, const int* in_sizes, int n_in,
                              void* d_out, int out_size, void* d_ws, size_t ws_size,
                              hipStream_t stream) {
  const float* params = (const float*)d_in[0];
  const float* randu = (const float*)d_in[1];
  float* out = (float*)d_out;
  char* ws = (char*)d_ws;
  if (ws_size >= Plan<double, double>().need) {
    run_cfg<double, double>(params, randu, out, ws, stream);
  } else if (ws_size >= Plan<float, double>().need) {
    run_cfg<float, double>(params, randu, out, ws, stream);
  } else if (ws_size >= Plan<float, float>().need) {
    run_cfg<float, float>(params, randu, out, ws, stream);
  } else {
    k_diag<<<dim3((out_size + 255) / 256), dim3(256), 0, stream>>>(
        out, out_size, (float)(ws_size >> 20));
  }
}